// Round 6
// baseline (455.642 us; speedup 1.0000x reference)
//
#include <hip/hip_runtime.h>
#include <hip/hip_bf16.h>
#include <stdint.h>

// Problem constants
#define IN_SIZE   4096            // K
#define OUT_SIZE  12288           // N
#define M_ROWS    4096            // M (x rows)
#define LN_EPS    1e-5f
#define N_BLOCKS  786432          // OUT_SIZE*IN_SIZE/64

typedef __attribute__((ext_vector_type(8))) short bf16x8;
typedef __attribute__((ext_vector_type(4))) float f32x4;
typedef __attribute__((ext_vector_type(16))) float f32x16;

__device__ __constant__ float NF4_CB[16] = {
    -1.0f, -0.6961928009986877f, -0.5250730514526367f, -0.39491748809814453f,
    -0.28444138169288635f, -0.18477343022823334f, -0.09105003625154495f, 0.0f,
    0.07958029955625534f, 0.16093020141124725f, 0.24611230194568634f,
    0.33791524171829224f, 0.44070982933044434f, 0.5626170039176941f,
    0.7229568362236023f, 1.0f };

__device__ __forceinline__ unsigned short f2bf(float f) {
    unsigned u = __builtin_bit_cast(unsigned, f);
    u += 0x7FFFu + ((u >> 16) & 1u);
    return (unsigned short)(u >> 16);
}

// -------------------- LayerNorm: f32 out + bf16 side copy --------------------
__global__ __launch_bounds__(256) void ln_kernel(
    const float* __restrict__ x, const float* __restrict__ gamma,
    const float* __restrict__ beta, float* __restrict__ out_f32,
    unsigned short* __restrict__ out_bf16)
{
    const int row = blockIdx.x;
    const int tid = threadIdx.x;
    const float4* x4 = (const float4*)(x + (size_t)row * IN_SIZE);

    float4 v[4];
    float sum = 0.f, ssq = 0.f;
#pragma unroll
    for (int i = 0; i < 4; ++i) {
        v[i] = x4[tid + i * 256];
        sum += v[i].x + v[i].y + v[i].z + v[i].w;
        ssq += v[i].x * v[i].x + v[i].y * v[i].y + v[i].z * v[i].z + v[i].w * v[i].w;
    }
#pragma unroll
    for (int off = 32; off > 0; off >>= 1) {
        sum += __shfl_down(sum, off, 64);
        ssq += __shfl_down(ssq, off, 64);
    }
    __shared__ float s_sum[4], s_ssq[4];
    const int wave = tid >> 6, lane = tid & 63;
    if (lane == 0) { s_sum[wave] = sum; s_ssq[wave] = ssq; }
    __syncthreads();
    sum = s_sum[0] + s_sum[1] + s_sum[2] + s_sum[3];
    ssq = s_ssq[0] + s_ssq[1] + s_ssq[2] + s_ssq[3];

    const float mu   = sum * (1.f / IN_SIZE);
    const float var  = ssq * (1.f / IN_SIZE) - mu * mu;
    const float rstd = rsqrtf(var + LN_EPS);

    const float4* g4 = (const float4*)gamma;
    const float4* b4 = (const float4*)beta;
    float4* o4 = (float4*)(out_f32 + (size_t)row * IN_SIZE);
    ushort4* ob4 = (ushort4*)(out_bf16 + (size_t)row * IN_SIZE);
#pragma unroll
    for (int i = 0; i < 4; ++i) {
        const int c = tid + i * 256;
        const float4 g = g4[c], b = b4[c];
        float4 y;
        y.x = (v[i].x - mu) * rstd * g.x + b.x;
        y.y = (v[i].y - mu) * rstd * g.y + b.y;
        y.z = (v[i].z - mu) * rstd * g.z + b.z;
        y.w = (v[i].w - mu) * rstd * g.w + b.w;
        o4[c] = y;
        ushort4 p;
        p.x = f2bf(y.x); p.y = f2bf(y.y); p.z = f2bf(y.z); p.w = f2bf(y.w);
        ob4[c] = p;
    }
}

// -------------------- NF4 dequant -> bf16 W [12288][4096] --------------------
__global__ __launch_bounds__(256) void dq_kernel(
    const int* __restrict__ codes, const int* __restrict__ qs,
    const float* __restrict__ qf, const float* __restrict__ smean,
    unsigned short* __restrict__ wout)
{
    __shared__ float cb[16];
    if (threadIdx.x < 16) cb[threadIdx.x] = NF4_CB[threadIdx.x];
    __syncthreads();

    const size_t t  = (size_t)blockIdx.x * 256 + threadIdx.x; // 8 elems/thread
    const size_t e0 = t * 8;
    const size_t blk = e0 >> 6;
    const float scale = (float)qs[blk] / qf[blk >> 8] + smean[0];

    const int4* c4 = (const int4*)(codes + e0);
    const int4 a = c4[0], b = c4[1];
    ushort4 lo, hi;
    lo.x = f2bf(cb[a.x] * scale); lo.y = f2bf(cb[a.y] * scale);
    lo.z = f2bf(cb[a.z] * scale); lo.w = f2bf(cb[a.w] * scale);
    hi.x = f2bf(cb[b.x] * scale); hi.y = f2bf(cb[b.y] * scale);
    hi.z = f2bf(cb[b.z] * scale); hi.w = f2bf(cb[b.w] * scale);
    *(ushort4*)(wout + e0)     = lo;
    *(ushort4*)(wout + e0 + 4) = hi;
}

// ==================== 256x256 pipelined bf16 GEMM (32x32x16 MFMA) ============
// C[M][N] = A[M][K] * B[N][K]^T ; BM=BN=256, BK=64, 512 thr (8 waves 2x4)
// Phase structure: {stage; [counted vmcnt]; barrier; ds_reads for NEXT
// subtile; MFMA current subtile}. 4 barriers/K-tile; 1 vmcnt/K-tile.
#define BKT 64
#define NT  (IN_SIZE / BKT)   // 64 K-tiles

#define GL16(src, dst) __builtin_amdgcn_global_load_lds( \
    (const __attribute__((address_space(1))) void*)(src), \
    (__attribute__((address_space(3))) void*)(dst), 16, 0, 0)

#define BAR_FENCE() do {                                  \
    __builtin_amdgcn_s_barrier();                         \
    __builtin_amdgcn_sched_barrier(0);                    \
    asm volatile("" ::: "memory");                        \
} while (0)

// One quadrant: 2 m-tiles x 1 n-tile x 4 k-steps = 8 MFMA (32x32x16).
// ks outer, m inner -> alternate acc chains for ILP.
template<int QM, int QN>
__device__ __forceinline__ void mmaq(f32x16 (&acc)[4][2],
    const bf16x8 (&a)[2][4], const bf16x8 (&b)[4]) {
    __builtin_amdgcn_s_setprio(1);
#pragma unroll
    for (int ks = 0; ks < 4; ++ks)
#pragma unroll
        for (int m = 0; m < 2; ++m)
            acc[QM * 2 + m][QN] = __builtin_amdgcn_mfma_f32_32x32x16_bf16(
                a[m][ks], b[ks], acc[QM * 2 + m][QN], 0, 0, 0);
    __builtin_amdgcn_s_setprio(0);
}

__global__ __launch_bounds__(512, 1) void gemm_kernel(
    const unsigned short* __restrict__ A,   // [M][K] bf16 bits
    const unsigned short* __restrict__ B,   // [N][K] bf16 bits
    float* __restrict__ C)                  // [M][N] f32
{
    extern __shared__ unsigned short lds[]; // 128 KiB
    // A slots: (buf*2+half)*8192 ushorts ; B slots: +32768

    const int tid  = threadIdx.x;
    const int lane = tid & 63;
    const int wid  = tid >> 6;
    const int wr   = wid >> 2;      // 0..1  (128-row half)
    const int wc   = wid & 3;       // 0..3  (64-col slice)
    const int l31  = lane & 31;
    const int lhi  = lane >> 5;     // k-group within 16-wide step
    const int l7   = lane & 7;      // row&7 for swizzle

    // XCD-aware bijective swizzle: nwg=768 (%8==0); each XCD gets 2 tm-rows
    constexpr int nwg = (M_ROWS / 256) * (OUT_SIZE / 256);  // 768
    const int orig = blockIdx.x;
    const int swz  = (orig & 7) * (nwg >> 3) + (orig >> 3);
    const int tm   = (swz / 96) * 2 + (swz & 1);
    const int tn   = (swz % 96) >> 1;

    // Staging: thread t, issue i -> LDS row = i*64 + t>>3, dest col8 = t&7,
    // pre-swizzled global col8 = (t&7) ^ (row&7)  (row&7 == (t>>3)&7)
    const int r0   = tid >> 3;
    const int c8s  = (tid & 7) ^ (r0 & 7);
    const unsigned short* Abase = A + (size_t)(tm * 256 + r0) * IN_SIZE + c8s * 8;
    const unsigned short* Bbase = B + (size_t)(tn * 256 + r0) * IN_SIZE + c8s * 8;

    auto stageA = [&](int T, int h, int buf) {
        const unsigned short* s = Abase + (size_t)h * 128 * IN_SIZE + (size_t)T * 64;
        unsigned short* d = lds + (buf * 2 + h) * 8192 + tid * 8;
        GL16(s, d);
        GL16(s + (size_t)64 * IN_SIZE, d + 4096);
    };
    auto stageB = [&](int T, int h, int buf) {
        const unsigned short* s = Bbase + (size_t)h * 128 * IN_SIZE + (size_t)T * 64;
        unsigned short* d = lds + 32768 + (buf * 2 + h) * 8192 + tid * 8;
        GL16(s, d);
        GL16(s + (size_t)64 * IN_SIZE, d + 4096);
    };
    // A-frag (32x32x16): row = qm*64 + m*32 + (lane&31), k-col8 = ks*2 + lhi,
    // swizzled col8 ^= row&7 (== lane&7).
    auto readA = [&](bf16x8 (&a)[2][4], int qm, int buf) {
#pragma unroll
        for (int m = 0; m < 2; ++m)
#pragma unroll
            for (int ks = 0; ks < 4; ++ks)
                a[m][ks] = *(const bf16x8*)(lds + (buf * 2 + wr) * 8192
                                                + (qm * 64 + m * 32 + l31) * 64
                                                + (((ks * 2 + lhi) ^ l7) * 8));
    };
    // B-frag: row-in-slot = (wc&1)*64 + qn*32 + (lane&31)
    auto readB = [&](bf16x8 (&b)[4], int qn, int buf) {
#pragma unroll
        for (int ks = 0; ks < 4; ++ks)
            b[ks] = *(const bf16x8*)(lds + 32768 + (buf * 2 + (wc >> 1)) * 8192
                                            + ((wc & 1) * 64 + qn * 32 + l31) * 64
                                            + (((ks * 2 + lhi) ^ l7) * 8));
    };

    f32x16 acc[4][2] = {};
    bf16x8 a0[2][4], a1[2][4], b0A[4], b0B[4], b1[4];

    // One K-tile. All LDS indices compile-time at expansion.
    // B0C = this tile's B(qn0) frags; B0N = next tile's (read p4).
    // a0 = this tile's A(qm0) (read prev p3); a1 = A(qm1) (read p2).
    // VM3: 0 = vmcnt(4) at p3, 1 = vmcnt(0) at p3, 2 = none.
#define TILE_BODY(T, BUF, B0C, B0N, DO_S1, DO_S2, VM3, DO_PRE)                \
    do {                                                                      \
        /* p1 */                                                              \
        if (DO_S1) stageA((T) + 1, 1, (BUF) ^ 1);                             \
        BAR_FENCE();                                                          \
        readB(b1, 1, (BUF));                                                  \
        mmaq<0, 0>(acc, a0, B0C);                                             \
        /* p2 */                                                              \
        if (DO_S2) stageB((T) + 2, 0, (BUF));                                 \
        BAR_FENCE();                                                          \
        readA(a1, 1, (BUF));                                                  \
        mmaq<0, 1>(acc, a0, b1);                                              \
        /* p3 */                                                              \
        if (DO_S2) stageB((T) + 2, 1, (BUF));                                 \
        if ((VM3) == 0) asm volatile("s_waitcnt vmcnt(4)" ::: "memory");      \
        else if ((VM3) == 1) asm volatile("s_waitcnt vmcnt(0)" ::: "memory"); \
        BAR_FENCE();                                                          \
        if (DO_PRE) readA(a0, 0, (BUF) ^ 1);                                  \
        mmaq<1, 0>(acc, a1, B0C);                                             \
        /* p4 */                                                              \
        if (DO_S2) stageA((T) + 2, 0, (BUF));                                 \
        BAR_FENCE();                                                          \
        if (DO_PRE) readB(B0N, 0, (BUF) ^ 1);                                 \
        mmaq<1, 1>(acc, a1, b1);                                              \
    } while (0)

    // Prologue: stage tile0 fully + tile1 {B0,B1,A0}; vmcnt(6) retires tile0;
    // then pre-read tile0's a0 and b0 fragments.
    stageA(0, 0, 0); stageA(0, 1, 0); stageB(0, 0, 0); stageB(0, 1, 0);
    stageB(1, 0, 1); stageB(1, 1, 1); stageA(1, 0, 1);
    asm volatile("s_waitcnt vmcnt(6)" ::: "memory");
    BAR_FENCE();
    readA(a0, 0, 0);
    readB(b0A, 0, 0);

    // Main loop: tiles 0..NT-3 (62 tiles, 31 double-iterations)
#pragma unroll 1
    for (int T = 0; T < NT - 2; T += 2) {
        TILE_BODY(T,     0, b0A, b0B, 1, 1, 0, 1);
        TILE_BODY(T + 1, 1, b0B, b0A, 1, 1, 0, 1);
    }
    // Tail: tile NT-2 stages only (NT-1,A1); p3 drains vmcnt(0); prefetch
    // NT-1 operands. Tile NT-1: pure compute.
    TILE_BODY(NT - 2, 0, b0A, b0B, 1, 0, 1, 1);
    TILE_BODY(NT - 1, 1, b0B, b0A, 0, 0, 2, 0);
#undef TILE_BODY

    // Epilogue: 32x32 C/D layout col=lane&31, row=(reg&3)+8*(reg>>2)+4*lhi
    const size_t crow0 = (size_t)(tm * 256 + wr * 128 + lhi * 4);
    const int    ccol0 = tn * 256 + wc * 64 + l31;
#pragma unroll
    for (int mt = 0; mt < 4; ++mt)
#pragma unroll
        for (int nt = 0; nt < 2; ++nt)
#pragma unroll
            for (int reg = 0; reg < 16; ++reg)
                C[(crow0 + mt * 32 + (reg & 3) + 8 * (reg >> 2)) * OUT_SIZE
                  + ccol0 + nt * 32] = acc[mt][nt][reg];
}

// -------------------- launch --------------------
extern "C" void kernel_launch(void* const* d_in, const int* in_sizes, int n_in,
                              void* d_out, int out_size, void* d_ws, size_t ws_size,
                              hipStream_t stream) {
    const float* x        = (const float*)d_in[0];
    const float* ln_w     = (const float*)d_in[1];
    const float* ln_b     = (const float*)d_in[2];
    const float* qf       = (const float*)d_in[3];
    const float* smean    = (const float*)d_in[4];
    const int*   codes    = (const int*)d_in[5];
    const int*   qscalers = (const int*)d_in[6];

    float* linear_out = (float*)d_out;                             // [4096][12288]
    float* ln_out     = (float*)d_out + (size_t)M_ROWS * OUT_SIZE; // [4096][4096]

    unsigned short* A_bf16 = (unsigned short*)d_ws;                // 32 MiB
    unsigned short* W_bf16 = (unsigned short*)((char*)d_ws + (size_t)M_ROWS * IN_SIZE * 2); // 96 MiB

    ln_kernel<<<M_ROWS, 256, 0, stream>>>(x, ln_w, ln_b, ln_out, A_bf16);

    const int dq_blocks = (N_BLOCKS * 64 / 8) / 256;  // 24576
    dq_kernel<<<dq_blocks, 256, 0, stream>>>(codes, qscalers, qf, smean, W_bf16);

    static bool attr_set = false;
    if (!attr_set) {
        (void)hipFuncSetAttribute((const void*)gemm_kernel,
                                  hipFuncAttributeMaxDynamicSharedMemorySize, 131072);
        attr_set = true;
    }
    const int gemm_blocks = (M_ROWS / 256) * (OUT_SIZE / 256); // 768
    gemm_kernel<<<gemm_blocks, 512, 131072, stream>>>(A_bf16, W_bf16, linear_out);
}

// Round 10
// 402.363 us; speedup vs baseline: 1.1324x; 1.1324x over previous
//
#include <hip/hip_runtime.h>
#include <hip/hip_bf16.h>
#include <stdint.h>

// Problem constants
#define IN_SIZE   4096            // K
#define OUT_SIZE  12288           // N
#define M_ROWS    4096            // M (x rows)
#define LN_EPS    1e-5f
#define N_BLOCKS  786432          // OUT_SIZE*IN_SIZE/64

typedef __attribute__((ext_vector_type(8))) short bf16x8;
typedef __attribute__((ext_vector_type(4))) float f32x4;

__device__ __constant__ float NF4_CB[16] = {
    -1.0f, -0.6961928009986877f, -0.5250730514526367f, -0.39491748809814453f,
    -0.28444138169288635f, -0.18477343022823334f, -0.09105003625154495f, 0.0f,
    0.07958029955625534f, 0.16093020141124725f, 0.24611230194568634f,
    0.33791524171829224f, 0.44070982933044434f, 0.5626170039176941f,
    0.7229568362236023f, 1.0f };

__device__ __forceinline__ unsigned short f2bf(float f) {
    unsigned u = __builtin_bit_cast(unsigned, f);
    u += 0x7FFFu + ((u >> 16) & 1u);
    return (unsigned short)(u >> 16);
}

// -------------------- LayerNorm: f32 out + bf16 side copy --------------------
__global__ __launch_bounds__(256) void ln_kernel(
    const float* __restrict__ x, const float* __restrict__ gamma,
    const float* __restrict__ beta, float* __restrict__ out_f32,
    unsigned short* __restrict__ out_bf16)
{
    const int row = blockIdx.x;
    const int tid = threadIdx.x;
    const float4* x4 = (const float4*)(x + (size_t)row * IN_SIZE);

    float4 v[4];
    float sum = 0.f, ssq = 0.f;
#pragma unroll
    for (int i = 0; i < 4; ++i) {
        v[i] = x4[tid + i * 256];
        sum += v[i].x + v[i].y + v[i].z + v[i].w;
        ssq += v[i].x * v[i].x + v[i].y * v[i].y + v[i].z * v[i].z + v[i].w * v[i].w;
    }
#pragma unroll
    for (int off = 32; off > 0; off >>= 1) {
        sum += __shfl_down(sum, off, 64);
        ssq += __shfl_down(ssq, off, 64);
    }
    __shared__ float s_sum[4], s_ssq[4];
    const int wave = tid >> 6, lane = tid & 63;
    if (lane == 0) { s_sum[wave] = sum; s_ssq[wave] = ssq; }
    __syncthreads();
    sum = s_sum[0] + s_sum[1] + s_sum[2] + s_sum[3];
    ssq = s_ssq[0] + s_ssq[1] + s_ssq[2] + s_ssq[3];

    const float mu   = sum * (1.f / IN_SIZE);
    const float var  = ssq * (1.f / IN_SIZE) - mu * mu;
    const float rstd = rsqrtf(var + LN_EPS);

    const float4* g4 = (const float4*)gamma;
    const float4* b4 = (const float4*)beta;
    float* o = out_f32 + (size_t)row * IN_SIZE;
    ushort4* ob4 = (ushort4*)(out_bf16 + (size_t)row * IN_SIZE);
#pragma unroll
    for (int i = 0; i < 4; ++i) {
        const int c = tid + i * 256;
        const float4 g = g4[c], b = b4[c];
        f32x4 y;
        y[0] = (v[i].x - mu) * rstd * g.x + b.x;
        y[1] = (v[i].y - mu) * rstd * g.y + b.y;
        y[2] = (v[i].z - mu) * rstd * g.z + b.z;
        y[3] = (v[i].w - mu) * rstd * g.w + b.w;
        // ln_out: streamed, never re-read -> nontemporal (ext-vector type ok)
        __builtin_nontemporal_store(y, (f32x4*)(o + c * 4));
        ushort4 p;
        p.x = f2bf(y[0]); p.y = f2bf(y[1]); p.z = f2bf(y[2]); p.w = f2bf(y[3]);
        ob4[c] = p;                               // A_bf16: re-read by GEMM, keep cached
    }
}

// -------------------- NF4 dequant -> bf16 W [12288][4096] --------------------
__global__ __launch_bounds__(256) void dq_kernel(
    const int* __restrict__ codes, const int* __restrict__ qs,
    const float* __restrict__ qf, const float* __restrict__ smean,
    unsigned short* __restrict__ wout)
{
    __shared__ float cb[16];
    if (threadIdx.x < 16) cb[threadIdx.x] = NF4_CB[threadIdx.x];
    __syncthreads();

    const size_t t  = (size_t)blockIdx.x * 256 + threadIdx.x; // 8 elems/thread
    const size_t e0 = t * 8;
    const size_t blk = e0 >> 6;
    const float scale = (float)qs[blk] / qf[blk >> 8] + smean[0];

    const int4* c4 = (const int4*)(codes + e0);
    const int4 a = c4[0], b = c4[1];
    ushort4 lo, hi;
    lo.x = f2bf(cb[a.x] * scale); lo.y = f2bf(cb[a.y] * scale);
    lo.z = f2bf(cb[a.z] * scale); lo.w = f2bf(cb[a.w] * scale);
    hi.x = f2bf(cb[b.x] * scale); hi.y = f2bf(cb[b.y] * scale);
    hi.z = f2bf(cb[b.z] * scale); hi.w = f2bf(cb[b.w] * scale);
    *(ushort4*)(wout + e0)     = lo;   // W: re-read by GEMM, keep cached
    *(ushort4*)(wout + e0 + 4) = hi;
}

// ==================== 256x256 pipelined bf16 GEMM (R5 verified) ==============
// C[M][N] = A[M][K] * B[N][K]^T ; BM=BN=256, BK=64, 512 thr (8 waves 2x4)
// Phase structure: {stage; [counted vmcnt]; barrier; ds_reads for NEXT
// subtile; MFMA current subtile}. Reads drain during MFMA windows
// (counted-lgkm pipelining); 4 barriers/K-tile; 1 vmcnt/K-tile.
#define BKT 64
#define NT  (IN_SIZE / BKT)   // 64 K-tiles

#define GL16(src, dst) __builtin_amdgcn_global_load_lds( \
    (const __attribute__((address_space(1))) void*)(src), \
    (__attribute__((address_space(3))) void*)(dst), 16, 0, 0)

// barrier + compiler fences: keep following ds_reads below the barrier
// (memory clobber) and block scheduler motion across it (sched_barrier).
#define BAR_FENCE() do {                                  \
    __builtin_amdgcn_s_barrier();                         \
    __builtin_amdgcn_sched_barrier(0);                    \
    asm volatile("" ::: "memory");                        \
} while (0)

template<int QM, int QN>
__device__ __forceinline__ void mmaq(f32x4 (&acc)[8][4],
    const bf16x8 (&a)[4][2], const bf16x8 (&b)[2][2]) {
    __builtin_amdgcn_s_setprio(1);
#pragma unroll
    for (int m = 0; m < 4; ++m)
#pragma unroll
        for (int n = 0; n < 2; ++n)
#pragma unroll
            for (int kk = 0; kk < 2; ++kk)
                acc[QM * 4 + m][QN * 2 + n] = __builtin_amdgcn_mfma_f32_16x16x32_bf16(
                    a[m][kk], b[n][kk], acc[QM * 4 + m][QN * 2 + n], 0, 0, 0);
    __builtin_amdgcn_s_setprio(0);
}

__global__ __launch_bounds__(512, 1) void gemm_kernel(
    const unsigned short* __restrict__ A,   // [M][K] bf16 bits
    const unsigned short* __restrict__ B,   // [N][K] bf16 bits
    float* __restrict__ C)                  // [M][N] f32
{
    extern __shared__ unsigned short lds[]; // 128 KiB
    // A slots: (buf*2+half)*8192 ushorts ; B slots: +32768

    const int tid  = threadIdx.x;
    const int lane = tid & 63;
    const int wid  = tid >> 6;
    const int wr   = wid >> 2;      // 0..1  (128-row half)
    const int wc   = wid & 3;       // 0..3  (64-col slice)
    const int fr   = lane & 15, fg = lane >> 4;
    const int frs  = fr & 7;

    // XCD-aware bijective swizzle: nwg=768 (%8==0); each XCD gets 2 tm-rows
    constexpr int nwg = (M_ROWS / 256) * (OUT_SIZE / 256);  // 768
    const int orig = blockIdx.x;
    const int swz  = (orig & 7) * (nwg >> 3) + (orig >> 3);
    const int tm   = (swz / 96) * 2 + (swz & 1);
    const int tn   = (swz % 96) >> 1;

    // Staging: thread t, issue i -> LDS row = i*64 + t>>3, dest col8 = t&7,
    // pre-swizzled global col8 = (t&7) ^ (row&7)  (row&7 == (t>>3)&7)
    const int r0   = tid >> 3;
    const int c8s  = (tid & 7) ^ (r0 & 7);
    const unsigned short* Abase = A + (size_t)(tm * 256 + r0) * IN_SIZE + c8s * 8;
    const unsigned short* Bbase = B + (size_t)(tn * 256 + r0) * IN_SIZE + c8s * 8;

    auto stageA = [&](int T, int h, int buf) {
        const unsigned short* s = Abase + (size_t)h * 128 * IN_SIZE + (size_t)T * 64;
        unsigned short* d = lds + (buf * 2 + h) * 8192 + tid * 8;
        GL16(s, d);
        GL16(s + (size_t)64 * IN_SIZE, d + 4096);
    };
    auto stageB = [&](int T, int h, int buf) {
        const unsigned short* s = Bbase + (size_t)h * 128 * IN_SIZE + (size_t)T * 64;
        unsigned short* d = lds + 32768 + (buf * 2 + h) * 8192 + tid * 8;
        GL16(s, d);
        GL16(s + (size_t)64 * IN_SIZE, d + 4096);
    };
    // ds_read fragments: logical col8 = kk*4+fg, swizzled ^= (row&7) == frs
    auto readA = [&](bf16x8 (&a)[4][2], int qm, int buf) {
#pragma unroll
        for (int m = 0; m < 4; ++m)
#pragma unroll
            for (int kk = 0; kk < 2; ++kk)
                a[m][kk] = *(const bf16x8*)(lds + (buf * 2 + wr) * 8192
                                                + (qm * 64 + m * 16 + fr) * 64
                                                + (((kk * 4 + fg) ^ frs) * 8));
    };
    auto readB = [&](bf16x8 (&b)[2][2], int qn, int buf) {
#pragma unroll
        for (int n = 0; n < 2; ++n)
#pragma unroll
            for (int kk = 0; kk < 2; ++kk)
                b[n][kk] = *(const bf16x8*)(lds + 32768 + (buf * 2 + (wc >> 1)) * 8192
                                                + ((wc & 1) * 64 + (qn * 2 + n) * 16 + fr) * 64
                                                + (((kk * 4 + fg) ^ frs) * 8));
    };

    f32x4 acc[8][4] = {};
    bf16x8 a0[4][2], a1[4][2], b0A[2][2], b0B[2][2], b1[2][2];

    // One K-tile. All LDS indices compile-time at expansion.
    // B0C = this tile's B(qn0) frags; B0N = next tile's (read p4).
    // a0 = this tile's A(qm0) (read in prev p3); a1 = A(qm1) (read p2).
    // VM3: 0 = vmcnt(4) at p3, 1 = vmcnt(0) at p3, 2 = none.
    // DO_PRE: read next tile's a0 (p3) and b0 (p4).
#define TILE_BODY(T, BUF, B0C, B0N, DO_S1, DO_S2, VM3, DO_PRE)                \
    do {                                                                      \
        /* p1 */                                                              \
        if (DO_S1) stageA((T) + 1, 1, (BUF) ^ 1);                             \
        BAR_FENCE();                                                          \
        readB(b1, 1, (BUF));                                                  \
        mmaq<0, 0>(acc, a0, B0C);                                             \
        /* p2 */                                                              \
        if (DO_S2) stageB((T) + 2, 0, (BUF));                                 \
        BAR_FENCE();                                                          \
        readA(a1, 1, (BUF));                                                  \
        mmaq<0, 1>(acc, a0, b1);                                              \
        /* p3 */                                                              \
        if (DO_S2) stageB((T) + 2, 1, (BUF));                                 \
        if ((VM3) == 0) asm volatile("s_waitcnt vmcnt(4)" ::: "memory");      \
        else if ((VM3) == 1) asm volatile("s_waitcnt vmcnt(0)" ::: "memory"); \
        BAR_FENCE();                                                          \
        if (DO_PRE) readA(a0, 0, (BUF) ^ 1);                                  \
        mmaq<1, 0>(acc, a1, B0C);                                             \
        /* p4 */                                                              \
        if (DO_S2) stageA((T) + 2, 0, (BUF));                                 \
        BAR_FENCE();                                                          \
        if (DO_PRE) readB(B0N, 0, (BUF) ^ 1);                                 \
        mmaq<1, 1>(acc, a1, b1);                                              \
    } while (0)

    // Prologue: stage tile0 fully + tile1 {B0,B1,A0}; vmcnt(6) retires tile0;
    // then pre-read tile0's a0 and b0 fragments.
    stageA(0, 0, 0); stageA(0, 1, 0); stageB(0, 0, 0); stageB(0, 1, 0);
    stageB(1, 0, 1); stageB(1, 1, 1); stageA(1, 0, 1);
    asm volatile("s_waitcnt vmcnt(6)" ::: "memory");
    BAR_FENCE();
    readA(a0, 0, 0);
    readB(b0A, 0, 0);

    // Main loop: tiles 0..NT-3 (62 tiles, 31 double-iterations)
#pragma unroll 1
    for (int T = 0; T < NT - 2; T += 2) {
        TILE_BODY(T,     0, b0A, b0B, 1, 1, 0, 1);
        TILE_BODY(T + 1, 1, b0B, b0A, 1, 1, 0, 1);
    }
    // Tail: tile NT-2 stages only (NT-1,A1); p3 drains vmcnt(0); prefetch
    // NT-1 operands. Tile NT-1: pure compute, no stages/waits/prefetch.
    TILE_BODY(NT - 2, 0, b0A, b0B, 1, 0, 1, 1);
    TILE_BODY(NT - 1, 1, b0B, b0A, 0, 0, 2, 0);
#undef TILE_BODY

    // Epilogue: C/D layout col=lane&15, row=(lane>>4)*4+j.
    // Nontemporal: C is write-once, never re-read -> don't evict B from L2/L3.
    const size_t crow0 = (size_t)(tm * 256 + wr * 128 + fg * 4);
    const int    ccol0 = tn * 256 + wc * 64 + fr;
#pragma unroll
    for (int mg = 0; mg < 8; ++mg)
#pragma unroll
        for (int ng = 0; ng < 4; ++ng)
#pragma unroll
            for (int j = 0; j < 4; ++j)
                __builtin_nontemporal_store(acc[mg][ng][j],
                    &C[(crow0 + mg * 16 + j) * OUT_SIZE + ccol0 + ng * 16]);
}

// -------------------- launch --------------------
extern "C" void kernel_launch(void* const* d_in, const int* in_sizes, int n_in,
                              void* d_out, int out_size, void* d_ws, size_t ws_size,
                              hipStream_t stream) {
    const float* x        = (const float*)d_in[0];
    const float* ln_w     = (const float*)d_in[1];
    const float* ln_b     = (const float*)d_in[2];
    const float* qf       = (const float*)d_in[3];
    const float* smean    = (const float*)d_in[4];
    const int*   codes    = (const int*)d_in[5];
    const int*   qscalers = (const int*)d_in[6];

    float* linear_out = (float*)d_out;                             // [4096][12288]
    float* ln_out     = (float*)d_out + (size_t)M_ROWS * OUT_SIZE; // [4096][4096]

    unsigned short* A_bf16 = (unsigned short*)d_ws;                // 32 MiB
    unsigned short* W_bf16 = (unsigned short*)((char*)d_ws + (size_t)M_ROWS * IN_SIZE * 2); // 96 MiB

    ln_kernel<<<M_ROWS, 256, 0, stream>>>(x, ln_w, ln_b, ln_out, A_bf16);

    const int dq_blocks = (N_BLOCKS * 64 / 8) / 256;  // 24576
    dq_kernel<<<dq_blocks, 256, 0, stream>>>(codes, qscalers, qf, smean, W_bf16);

    static bool attr_set = false;
    if (!attr_set) {
        (void)hipFuncSetAttribute((const void*)gemm_kernel,
                                  hipFuncAttributeMaxDynamicSharedMemorySize, 131072);
        attr_set = true;
    }
    const int gemm_blocks = (M_ROWS / 256) * (OUT_SIZE / 256); // 768
    gemm_kernel<<<gemm_blocks, 512, 131072, stream>>>(A_bf16, W_bf16, linear_out);
}